// Round 7
// baseline (876.058 us; speedup 1.0000x reference)
//
#include <hip/hip_runtime.h>
#include <cstdint>

typedef unsigned short u16;
typedef __attribute__((ext_vector_type(8))) short bf16x8;
typedef __attribute__((ext_vector_type(4))) float f32x4;

#define DIM   1024
#define BATCH 4
#define SEQ   4096
#define E3    3072
#define MTOT  (BATCH*SEQ)   // 16384

// ---------- bf16 helpers (RNE) ----------
__device__ __forceinline__ u16 f2bf(float x) {
    union { float f; unsigned u; } v; v.f = x;
    unsigned r = v.u + 0x7FFFu + ((v.u >> 16) & 1u);
    return (u16)(r >> 16);
}

// ---------- async global->LDS 16B ----------
__device__ __forceinline__ void gl16(const void* g, void* l) {
    __builtin_amdgcn_global_load_lds(
        (const __attribute__((address_space(1))) void*)g,
        (__attribute__((address_space(3))) void*)l, 16, 0, 0);
}

// ---------------------------------------------------------------------------
// GEMM mainloop: C[128x128] += A * B^T, both bf16 k-major, K mult of 32.
// 256 thr = 4 waves 2x2; wave = 4x4 MFMA 16x16x32 tiles.
// LDS fragment-identity chunks: lane L <-> (row L&15, kq L>>4), 16B each.
// ---------------------------------------------------------------------------
__device__ __forceinline__ void gemm_main(
    const u16* __restrict__ A, int sA,
    const u16* __restrict__ B, int sB,
    int K, int m0, int n0,
    u16* sAs, u16* sBs,
    f32x4 acc[4][4])
{
    const int t  = threadIdx.x;
    const int w  = t >> 6, L = t & 63;
    const int rL = L & 15, kq = L >> 4;
    const int c0 = 2*w;

    const size_t a0 = (size_t)(m0 + c0*16 + rL)*sA + kq*8;
    const size_t a1 = a0 + (size_t)16*sA;
    const size_t b0 = (size_t)(n0 + c0*16 + rL)*sB + kq*8;
    const size_t b1 = b0 + (size_t)16*sB;
    u16* lA0 = sAs + c0*512; u16* lA1 = lA0 + 512;
    u16* lB0 = sBs + c0*512; u16* lB1 = lB0 + 512;

    const int cm = 4*(w>>1), cn = 4*(w&1);

    for (int k0 = 0; k0 < K; k0 += 32) {
        __syncthreads();
        gl16(A + a0 + k0, lA0); gl16(A + a1 + k0, lA1);
        gl16(B + b0 + k0, lB0); gl16(B + b1 + k0, lB1);
        __syncthreads();

        bf16x8 av[4], bv[4];
        #pragma unroll
        for (int i = 0; i < 4; ++i) {
            av[i] = *(const bf16x8*)&sAs[(cm+i)*512 + L*8];
            bv[i] = *(const bf16x8*)&sBs[(cn+i)*512 + L*8];
        }
        #pragma unroll
        for (int mt = 0; mt < 4; ++mt)
            #pragma unroll
            for (int nt = 0; nt < 4; ++nt)
                acc[mt][nt] = __builtin_amdgcn_mfma_f32_16x16x32_bf16(av[mt], bv[nt], acc[mt][nt], 0,0,0);
    }
}

// ---------------------------------------------------------------------------
// elementwise: fp32 -> bf16
// ---------------------------------------------------------------------------
__global__ __launch_bounds__(256)
void cvt_bf16(const float* __restrict__ x, u16* __restrict__ y) {
    size_t i = ((size_t)blockIdx.x*256 + threadIdx.x)*4;
    float4 v = *(const float4*)&x[i];
    ushort4 h;
    h.x = f2bf(v.x); h.y = f2bf(v.y); h.z = f2bf(v.z); h.w = f2bf(v.w);
    *(ushort4*)&y[i] = h;
}

// ---------------------------------------------------------------------------
// QKV GEMM (flat grid 3072, XCD-pinned n-strips):
//   xcd = bid&7 owns n-tiles {xcd, xcd+8, xcd+16}; m streams within.
// Epilogue: Q pre-scaled 1/32 (pair-packed u32), K (pair-packed), Vt ushort4.
// ---------------------------------------------------------------------------
__global__ __launch_bounds__(256,4)
void gemm_qkv(const u16* __restrict__ Xbf, const u16* __restrict__ Wbf,
              const float* __restrict__ bias,
              u16* __restrict__ Qh, u16* __restrict__ Kh,
              u16* __restrict__ Vth)
{
    __shared__ __align__(16) u16 sA[4096], sB[4096];
    f32x4 acc[4][4];
    #pragma unroll
    for (int i=0;i<4;++i)
        #pragma unroll
        for (int j=0;j<4;++j) acc[i][j] = (f32x4){0.f,0.f,0.f,0.f};

    const int bid = blockIdx.x;
    const int xcd = bid & 7, rest = bid >> 3;       // rest 0..383
    const int mI  = rest & 127, ng = rest >> 7;     // ng 0..2
    const int m0 = mI*128, n0 = (xcd + 8*ng)*128;
    gemm_main(Xbf, DIM, Wbf, DIM, DIM, m0, n0, sA, sB, acc);

    const int t = threadIdx.x, w = t>>6, L = t&63;
    const int wm = 64*(w>>1), wn = 64*(w&1);
    const int cl = L&15, rq = (L>>4)*4;
    const int region = n0 >> 10;
    const float qscale = 0.03125f;

    if (region < 2) {
        u16* Dst = region ? Kh : Qh;
        const float fs = region ? 1.0f : qscale;
        #pragma unroll
        for (int nt = 0; nt < 4; ++nt) {
            float bc = bias[n0 + wn + nt*16 + cl];
            #pragma unroll
            for (int mt = 0; mt < 4; ++mt)
                #pragma unroll
                for (int r = 0; r < 4; ++r)
                    acc[mt][nt][r] = (acc[mt][nt][r] + bc)*fs;
        }
        const int d0 = (n0 & 1023) + wn;
        #pragma unroll
        for (int p = 0; p < 2; ++p) {
            const int nt0 = 2*p, nt1 = 2*p+1;
            #pragma unroll
            for (int mt = 0; mt < 4; ++mt) {
                int row0 = m0 + wm + mt*16 + rq;
                int bi = row0 >> 12, s0 = row0 & (SEQ-1);
                #pragma unroll
                for (int r = 0; r < 4; ++r) {
                    float v0 = acc[mt][nt0][r], v1 = acc[mt][nt1][r];
                    float x0 = __shfl_xor(v0, 1, 64);
                    float x1 = __shfl_xor(v1, 1, 64);
                    unsigned wv; int colb;
                    if ((cl & 1) == 0) {
                        wv   = (unsigned)f2bf(v0) | ((unsigned)f2bf(x0) << 16);
                        colb = nt0*16 + cl;
                    } else {
                        wv   = (unsigned)f2bf(x1) | ((unsigned)f2bf(v1) << 16);
                        colb = nt1*16 + (cl-1);
                    }
                    size_t idx = ((size_t)bi*SEQ + s0 + r)*DIM + d0 + colb;
                    *(unsigned*)&Dst[idx] = wv;
                }
            }
        }
    } else {
        #pragma unroll
        for (int nt = 0; nt < 4; ++nt) {
            int col = n0 + wn + nt*16 + cl;
            float bc = bias[col];
            int d = col & (DIM-1);
            #pragma unroll
            for (int mt = 0; mt < 4; ++mt) {
                int row0 = m0 + wm + mt*16 + rq;
                int bi = row0 >> 12, s0 = row0 & (SEQ-1);
                ushort4 hv;
                hv.x = f2bf(acc[mt][nt][0] + bc);
                hv.y = f2bf(acc[mt][nt][1] + bc);
                hv.z = f2bf(acc[mt][nt][2] + bc);
                hv.w = f2bf(acc[mt][nt][3] + bc);
                size_t base = ((size_t)bi*DIM + d)*SEQ + s0;
                *(ushort4*)&Vth[base] = hv;
            }
        }
    }
}

// ---------------------------------------------------------------------------
// Scores (flat grid 4096, XCD-pinned): xcd owns n ∈ {xcd+8*ng}, K-strip
// (128x1024 bf16 = 256 KB) stays L2-resident; m and b stream within XCD.
// ---------------------------------------------------------------------------
__global__ __launch_bounds__(256,4)
void gemm_scores(const u16* __restrict__ Qh, const u16* __restrict__ Kh,
                 u16* __restrict__ S0, u16* __restrict__ S1,
                 u16* __restrict__ S2, u16* __restrict__ S3)
{
    __shared__ __align__(16) u16 sA[4096], sB[4096];
    f32x4 acc[4][4];
    #pragma unroll
    for (int i=0;i<4;++i)
        #pragma unroll
        for (int j=0;j<4;++j) acc[i][j] = (f32x4){0.f,0.f,0.f,0.f};

    const int bid = blockIdx.x;
    const int xcd = bid & 7, rest = bid >> 3;        // rest 0..511
    const int mI = rest & 31, r2 = rest >> 5;        // r2 0..15
    const int bz = r2 & 3, ng = r2 >> 2;             // ng 0..3
    const int m0 = mI*128, n0 = (xcd + 8*ng)*128;
    const size_t qo = (size_t)bz*SEQ*DIM;
    gemm_main(Qh + qo, DIM, Kh + qo, DIM, DIM, m0, n0, sA, sB, acc);

    u16* Sb = (bz == 0) ? S0 : (bz == 1) ? S1 : (bz == 2) ? S2 : S3;
    const int t = threadIdx.x, w = t>>6, L = t&63;
    const int wm = 64*(w>>1), wn = 64*(w&1);
    const int cl = L&15, rq = (L>>4)*4;
    #pragma unroll
    for (int p = 0; p < 2; ++p) {
        const int nt0 = 2*p, nt1 = 2*p+1;
        #pragma unroll
        for (int mt = 0; mt < 4; ++mt) {
            int row0 = m0 + wm + mt*16 + rq;
            #pragma unroll
            for (int r = 0; r < 4; ++r) {
                float v0 = acc[mt][nt0][r], v1 = acc[mt][nt1][r];
                float x0 = __shfl_xor(v0, 1, 64);
                float x1 = __shfl_xor(v1, 1, 64);
                unsigned wv; int colb;
                if ((cl & 1) == 0) {
                    wv   = (unsigned)f2bf(v0) | ((unsigned)f2bf(x0) << 16);
                    colb = nt0*16 + cl;
                } else {
                    wv   = (unsigned)f2bf(x1) | ((unsigned)f2bf(v1) << 16);
                    colb = nt1*16 + (cl-1);
                }
                *(unsigned*)&Sb[(size_t)(row0 + r)*SEQ + n0 + wn + colb] = wv;
            }
        }
    }
}

// ---------------------------------------------------------------------------
// Row softmax over bf16 S (pre-scaled scores), P bf16 in place. 16384 rows.
// ---------------------------------------------------------------------------
__global__ __launch_bounds__(256)
void softmax_pack(u16* __restrict__ S0, u16* __restrict__ S1,
                  u16* __restrict__ S2, u16* __restrict__ S3)
{
    __shared__ float red[4];
    const int t = threadIdx.x, L = t & 63, w = t >> 6;
    const int gr = blockIdx.x, bz = gr >> 12, rr = gr & (SEQ-1);
    u16* Sb = (bz == 0) ? S0 : (bz == 1) ? S1 : (bz == 2) ? S2 : S3;
    u16* row = Sb + (size_t)rr*SEQ;

    float v[16];
    float m = -1e30f;
    #pragma unroll
    for (int j = 0; j < 2; ++j) {
        ushort4 x0 = *(const ushort4*)&row[t*8 + j*2048];
        ushort4 x1 = *(const ushort4*)&row[t*8 + j*2048 + 4];
        union { unsigned u; float f; } c;
        c.u = (unsigned)x0.x << 16; v[8*j+0] = c.f;
        c.u = (unsigned)x0.y << 16; v[8*j+1] = c.f;
        c.u = (unsigned)x0.z << 16; v[8*j+2] = c.f;
        c.u = (unsigned)x0.w << 16; v[8*j+3] = c.f;
        c.u = (unsigned)x1.x << 16; v[8*j+4] = c.f;
        c.u = (unsigned)x1.y << 16; v[8*j+5] = c.f;
        c.u = (unsigned)x1.z << 16; v[8*j+6] = c.f;
        c.u = (unsigned)x1.w << 16; v[8*j+7] = c.f;
    }
    #pragma unroll
    for (int i = 0; i < 16; ++i) m = fmaxf(m, v[i]);
    #pragma unroll
    for (int off = 32; off; off >>= 1) m = fmaxf(m, __shfl_xor(m, off, 64));
    if (L == 0) red[w] = m;
    __syncthreads();
    m = fmaxf(fmaxf(red[0],red[1]), fmaxf(red[2],red[3]));

    float s = 0.f;
    #pragma unroll
    for (int i = 0; i < 16; ++i) { v[i] = __expf(v[i] - m); s += v[i]; }
    #pragma unroll
    for (int off = 32; off; off >>= 1) s += __shfl_xor(s, off, 64);
    __syncthreads();
    if (L == 0) red[w] = s;
    __syncthreads();
    s = red[0]+red[1]+red[2]+red[3];
    const float inv = 1.0f / s;

    #pragma unroll
    for (int j = 0; j < 2; ++j) {
        ushort4 h0, h1;
        h0.x = f2bf(v[8*j+0]*inv); h0.y = f2bf(v[8*j+1]*inv);
        h0.z = f2bf(v[8*j+2]*inv); h0.w = f2bf(v[8*j+3]*inv);
        h1.x = f2bf(v[8*j+4]*inv); h1.y = f2bf(v[8*j+5]*inv);
        h1.z = f2bf(v[8*j+6]*inv); h1.w = f2bf(v[8*j+7]*inv);
        *(ushort4*)&row[t*8 + j*2048]     = h0;
        *(ushort4*)&row[t*8 + j*2048 + 4] = h1;
    }
}

// ---------------------------------------------------------------------------
// PV (flat grid 1024, XCD-pinned): exactly 8 n-tiles -> XCD i owns n-tile i;
// its Vt strip (1 MB x 4 batches) stays in the XCD's 4 MB L2; each P tile
// is read once per XCD. m inner, b outer.
// ---------------------------------------------------------------------------
__global__ __launch_bounds__(256,4)
void gemm_pv(const u16* __restrict__ P0, const u16* __restrict__ P1,
             const u16* __restrict__ P2, const u16* __restrict__ P3,
             const u16* __restrict__ Vth,
             float* __restrict__ O0, float* __restrict__ O1,
             float* __restrict__ O2, float* __restrict__ O3)
{
    __shared__ __align__(16) u16 sA[4096], sB[4096];
    f32x4 acc[4][4];
    #pragma unroll
    for (int i=0;i<4;++i)
        #pragma unroll
        for (int j=0;j<4;++j) acc[i][j] = (f32x4){0.f,0.f,0.f,0.f};

    const int bid = blockIdx.x;
    const int xcd = bid & 7, rest = bid >> 3;   // rest 0..127
    const int mI = rest & 31, bz = rest >> 5;
    const int m0 = mI*128, n0 = xcd*128;

    const u16* Pb = (bz == 0) ? P0 : (bz == 1) ? P1 : (bz == 2) ? P2 : P3;
    float*     Ob = (bz == 0) ? O0 : (bz == 1) ? O1 : (bz == 2) ? O2 : O3;
    gemm_main(Pb, SEQ, Vth + (size_t)bz*DIM*SEQ, SEQ, SEQ, m0, n0, sA, sB, acc);

    const int t = threadIdx.x, w = t>>6, L = t&63;
    const int wm = 64*(w>>1), wn = 64*(w&1);
    const int cl = L&15, rq = (L>>4)*4;
    #pragma unroll
    for (int nt = 0; nt < 4; ++nt) {
        int col = n0 + wn + nt*16 + cl;
        #pragma unroll
        for (int mt = 0; mt < 4; ++mt) {
            int row0 = m0 + wm + mt*16 + rq;
            #pragma unroll
            for (int r = 0; r < 4; ++r)
                Ob[(size_t)(row0 + r)*DIM + col] = acc[mt][nt][r];
        }
    }
}

// ---------------------------------------------------------------------------
// linear copy (float4), for O2/O3 parked in ws -> d_out second half
// ---------------------------------------------------------------------------
__global__ __launch_bounds__(256)
void copy_out(const float* __restrict__ src, float* __restrict__ dst)
{
    size_t i = ((size_t)blockIdx.x*256 + threadIdx.x)*4;
    *(float4*)&dst[i] = *(const float4*)&src[i];
}

// ---------------------------------------------------------------------------
extern "C" void kernel_launch(void* const* d_in, const int* in_sizes, int n_in,
                              void* d_out, int out_size, void* d_ws, size_t ws_size,
                              hipStream_t stream) {
    const float* X    = (const float*)d_in[0];
    const float* W    = (const float*)d_in[1];
    const float* bias = (const float*)d_in[2];
    float* out = (float*)d_out;

    const size_t MB = (size_t)1 << 20;
    if (ws_size < 192*MB) return;
    char* ws = (char*)d_ws;
    char* wo = (char*)d_out;
    // ws: Qh[0,32) Kh[32,64) Vth[64,96) S0[96,128) S1[128,160) S2[160,192)
    u16* Qh  = (u16*)ws;
    u16* Kh  = (u16*)(ws + 32*MB);
    u16* Vth = (u16*)(ws + 64*MB);
    u16* S0  = (u16*)(ws + 96*MB);
    u16* S1  = (u16*)(ws + 128*MB);
    u16* S2  = (u16*)(ws + 160*MB);
    // d_out during prologue: Xbf[0,32) Wbf[32,38); during attention: S3[32,64)
    u16* Xbf = (u16*)wo;
    u16* Wbf = (u16*)(wo + 32*MB);
    u16* S3  = (u16*)(wo + 32*MB);
    // pv outputs: O0,O1 -> d_out[0,32); O2,O3 -> dead Qh/Kh-front ws[0,32)
    float* O0 = (float*)wo;
    float* O1 = (float*)(wo + 16*MB);
    float* O2 = (float*)ws;
    float* O3 = (float*)(ws + 16*MB);

    cvt_bf16<<<MTOT*DIM/1024, 256, 0, stream>>>(X, Xbf);
    cvt_bf16<<<E3*DIM/1024,   256, 0, stream>>>(W, Wbf);

    gemm_qkv<<<E3/128 * MTOT/128, 256, 0, stream>>>(
        Xbf, Wbf, bias, Qh, Kh, Vth);

    gemm_scores<<<SEQ/128 * SEQ/128 * BATCH, 256, 0, stream>>>(
        Qh, Kh, S0, S1, S2, S3);

    softmax_pack<<<MTOT, 256, 0, stream>>>(S0, S1, S2, S3);

    gemm_pv<<<DIM/128 * SEQ/128 * BATCH, 256, 0, stream>>>(
        S0, S1, S2, S3, Vth, O0, O1, O2, O3);

    // O2,O3 (32 MB in ws) -> d_out[32,64)
    copy_out<<<(32*MB/sizeof(float))/1024, 256, 0, stream>>>(
        (const float*)ws, out + 8*MB);   // 8M floats = 32 MB offset
}